// Round 1
// baseline (1336.664 us; speedup 1.0000x reference)
//
#include <hip/hip_runtime.h>

#define EPS 1e-7f
#define MAX_NORM (1.0f - 1e-5f)

typedef __attribute__((ext_vector_type(8))) short bf16x8;
typedef __attribute__((ext_vector_type(4))) float f32x4;

__device__ __forceinline__ short f2bf(float f){
  unsigned u = __builtin_bit_cast(unsigned, f);
  u = (u + 0x7fffu + ((u >> 16) & 1u)) >> 16;
  return (short)u;
}

// ---- setup: s = tanh(||b||) * b / ||b||, s_buf[256] = s, s_buf[256] (extra) = ||s||^2 ----
__global__ void setup_s_kernel(const float* __restrict__ b, float* __restrict__ s_buf){
  __shared__ float redv[256];
  int t = threadIdx.x;
  float v = b[t];
  redv[t] = v * v;
  __syncthreads();
  for (int off = 128; off > 0; off >>= 1){
    if (t < off) redv[t] += redv[t + off];
    __syncthreads();
  }
  float bn = sqrtf(redv[0]);
  float th = tanhf(bn);
  s_buf[t] = th * v / fmaxf(bn, EPS);
  if (t == 0) s_buf[256] = th * th;
}

// ---- setup: W fp32 [256][256] -> bf16 in B-fragment-native layout ----
// flat = (((n>>4)*8 + ks)*4 + q)*16 + (n&15))*8 + j  with k = ks*32 + q*8 + j
__global__ void conv_w_kernel(const float* __restrict__ W, short* __restrict__ WB){
  int idx = blockIdx.x * 256 + threadIdx.x;
  int n = idx >> 8, k = idx & 255;
  int ks = k >> 5, q = (k >> 3) & 3, j = k & 7;
  int dst = ((((n >> 4) * 8 + ks) * 4 + q) * 16 + (n & 15)) * 8 + j;
  WB[dst] = f2bf(W[idx]);
}

// ---- main fused kernel: 64 rows x 256 cols per workgroup ----
// No A-tile LDS staging: each wave loads x fragments straight from global
// (L1/L2-coalesced), converts fp32->bf16 in-register, and runs the MFMA
// K-loop barrier-free. Only the cross-wave epilogue reduction uses LDS.
__global__ __launch_bounds__(256, 4)
void hyp_main(const float* __restrict__ x, const short* __restrict__ WB,
              const float* __restrict__ s_buf, float* __restrict__ out){
  __shared__ float redp[4][64][2];
  __shared__ float pq[64][2];
  __shared__ float xn2s[64];

  const int tid = threadIdx.x;
  const int wave = tid >> 6, lane = tid & 63;
  const int quad = lane >> 4, l15 = lane & 15;
  const int m0 = blockIdx.x * 64;

  f32x4 acc[4][4];
  #pragma unroll
  for (int mt = 0; mt < 4; mt++)
    #pragma unroll
    for (int tn = 0; tn < 4; tn++) acc[mt][tn] = (f32x4){0.f, 0.f, 0.f, 0.f};

  float pn[4] = {0.f, 0.f, 0.f, 0.f};   // fp32 row-norm partials (row mt*16+l15, this quad's k-slices)

  const bf16x8* WBv = (const bf16x8*)WB;
  // lane's A base: row m0 + l15 (+ mt*16), k-offset quad*8 (+ ks*32)
  const float* xb = x + (size_t)(m0 + l15) * 256 + quad * 8;

  #pragma unroll
  for (int ks = 0; ks < 8; ks++){
    bf16x8 bfrag[4];
    #pragma unroll
    for (int tn = 0; tn < 4; tn++)
      bfrag[tn] = WBv[((wave * 4 + tn) * 8 + ks) * 64 + lane];

    bf16x8 afrag[4];
    #pragma unroll
    for (int mt = 0; mt < 4; mt++){
      const float4* p = (const float4*)(xb + mt * 4096 + ks * 32);
      float4 v0 = p[0];
      float4 v1 = p[1];
      bf16x8 a;
      a[0] = f2bf(v0.x); a[1] = f2bf(v0.y); a[2] = f2bf(v0.z); a[3] = f2bf(v0.w);
      a[4] = f2bf(v1.x); a[5] = f2bf(v1.y); a[6] = f2bf(v1.z); a[7] = f2bf(v1.w);
      afrag[mt] = a;
      pn[mt] += v0.x*v0.x + v0.y*v0.y + v0.z*v0.z + v0.w*v0.w
              + v1.x*v1.x + v1.y*v1.y + v1.z*v1.z + v1.w*v1.w;
    }

    #pragma unroll
    for (int mt = 0; mt < 4; mt++)
      #pragma unroll
      for (int tn = 0; tn < 4; tn++)
        acc[mt][tn] = __builtin_amdgcn_mfma_f32_16x16x32_bf16(afrag[mt], bfrag[tn], acc[mt][tn], 0, 0, 0);
  }

  // x row norms: each lane holds the partial for (row mt*16+l15, its quad's k-slices);
  // butterfly over the quad bits (lane^16, lane^32) gives the full per-row sum.
  #pragma unroll
  for (int mt = 0; mt < 4; mt++){
    pn[mt] += __shfl_xor(pn[mt], 16, 64);
    pn[mt] += __shfl_xor(pn[mt], 32, 64);
  }
  if (tid < 16){   // wave 0, quad 0: publish (all waves hold identical values)
    #pragma unroll
    for (int mt = 0; mt < 4; mt++) xn2s[mt * 16 + l15] = pn[mt];
  }

  // epilogue: per-row sum(mx^2), sum(mx*s)
  float sv[4];
  #pragma unroll
  for (int tn = 0; tn < 4; tn++) sv[tn] = s_buf[wave * 64 + tn * 16 + l15];

  float msq[4][4], mds[4][4];
  #pragma unroll
  for (int mt = 0; mt < 4; mt++)
    #pragma unroll
    for (int r = 0; r < 4; r++){
      float a = 0.f, d = 0.f;
      #pragma unroll
      for (int tn = 0; tn < 4; tn++){ float c = acc[mt][tn][r]; a += c * c; d += c * sv[tn]; }
      msq[mt][r] = a; mds[mt][r] = d;
    }
  #pragma unroll
  for (int m = 1; m < 16; m <<= 1){
    #pragma unroll
    for (int mt = 0; mt < 4; mt++)
      #pragma unroll
      for (int r = 0; r < 4; r++){
        msq[mt][r] += __shfl_xor(msq[mt][r], m, 64);
        mds[mt][r] += __shfl_xor(mds[mt][r], m, 64);
      }
  }
  if (l15 == 0){
    #pragma unroll
    for (int mt = 0; mt < 4; mt++)
      #pragma unroll
      for (int r = 0; r < 4; r++){
        int row = mt * 16 + quad * 4 + r;
        redp[wave][row][0] = msq[mt][r];
        redp[wave][row][1] = mds[mt][r];
      }
  }
  __syncthreads();

  // per-row scalars P, Q (threads 0..63)
  if (tid < 64){
    int row = tid;
    float ms  = redp[0][row][0] + redp[1][row][0] + redp[2][row][0] + redp[3][row][0];
    float md  = redp[0][row][1] + redp[1][row][1] + redp[2][row][1] + redp[3][row][1];
    float xn2 = xn2s[row];
    float s2 = s_buf[256];
    float xn = fmaxf(sqrtf(xn2), EPS);
    float xc = fminf(xn, 1.0f - 1e-7f);
    float art = 0.5f * (log1pf(xc) - log1pf(-xc));
    float mxn = fmaxf(sqrtf(ms), EPS);
    float tt = tanhf(mxn / xn * art);
    float te = fminf(tt, MAX_NORM);      // proj(res): ||res|| = t
    float sr = te / mxn;                 // res = sr * mx
    float r2 = te * te;
    float xy = sr * md;                  // <res, s>
    float aa = 1.0f + 2.0f * xy + s2;
    float bc = 1.0f - r2;
    float den = fmaxf(1.0f + 2.0f * xy + r2 * s2, EPS);
    float P = aa * sr / den, Q = bc / den;
    float num2 = aa * aa * r2 + 2.0f * aa * bc * xy + bc * bc * s2;
    float on = fmaxf(sqrtf(num2) / den, EPS);
    if (on > MAX_NORM){ float fsc = MAX_NORM / on; P *= fsc; Q *= fsc; }
    pq[row][0] = P; pq[row][1] = Q;
  }
  __syncthreads();

  // store: out = P*mx + Q*s
  float* orow = out + (size_t)m0 * 256;
  #pragma unroll
  for (int mt = 0; mt < 4; mt++)
    #pragma unroll
    for (int r = 0; r < 4; r++){
      int row = mt * 16 + quad * 4 + r;
      float P = pq[row][0], Q = pq[row][1];
      #pragma unroll
      for (int tn = 0; tn < 4; tn++)
        orow[(size_t)row * 256 + wave * 64 + tn * 16 + l15] = P * acc[mt][tn][r] + Q * sv[tn];
    }
}

extern "C" void kernel_launch(void* const* d_in, const int* in_sizes, int n_in,
                              void* d_out, int out_size, void* d_ws, size_t ws_size,
                              hipStream_t stream){
  const float* x = (const float*)d_in[0];
  const float* W = (const float*)d_in[1];
  const float* b = (const float*)d_in[2];
  float* out = (float*)d_out;

  short* WB    = (short*)d_ws;                          // 256*256 bf16 = 128 KB
  float* s_buf = (float*)((char*)d_ws + 256 * 256 * 2); // 257 floats

  int N = in_sizes[0] / 256;

  setup_s_kernel<<<1, 256, 0, stream>>>(b, s_buf);
  conv_w_kernel<<<256, 256, 0, stream>>>(W, WB);
  hyp_main<<<N / 64, 256, 0, stream>>>(x, WB, s_buf, out);
}

// Round 3
// 505.431 us; speedup vs baseline: 2.6446x; 2.6446x over previous
//
#include <hip/hip_runtime.h>

#define EPS 1e-7f
#define MAX_NORM (1.0f - 1e-5f)

typedef __attribute__((ext_vector_type(8))) short bf16x8;
typedef __attribute__((ext_vector_type(4))) float f32x4;

__device__ __forceinline__ short f2bf(float f){
  unsigned u = __builtin_bit_cast(unsigned, f);
  u = (u + 0x7fffu + ((u >> 16) & 1u)) >> 16;
  return (short)u;
}

// ---- setup: s = tanh(||b||) * b / ||b||, s_buf[256] = s, s_buf[256] (extra) = ||s||^2 ----
__global__ void setup_s_kernel(const float* __restrict__ b, float* __restrict__ s_buf){
  __shared__ float redv[256];
  int t = threadIdx.x;
  float v = b[t];
  redv[t] = v * v;
  __syncthreads();
  for (int off = 128; off > 0; off >>= 1){
    if (t < off) redv[t] += redv[t + off];
    __syncthreads();
  }
  float bn = sqrtf(redv[0]);
  float th = tanhf(bn);
  s_buf[t] = th * v / fmaxf(bn, EPS);
  if (t == 0) s_buf[256] = th * th;
}

// ---- setup: W fp32 [256][256] -> bf16 in B-fragment-native layout ----
// flat = (((n>>4)*8 + ks)*4 + q)*16 + (n&15))*8 + j  with k = ks*32 + q*8 + j
__global__ void conv_w_kernel(const float* __restrict__ W, short* __restrict__ WB){
  int idx = blockIdx.x * 256 + threadIdx.x;
  int n = idx >> 8, k = idx & 255;
  int ks = k >> 5, q = (k >> 3) & 3, j = k & 7;
  int dst = ((((n >> 4) * 8 + ks) * 4 + q) * 16 + (n & 15)) * 8 + j;
  WB[dst] = f2bf(W[idx]);
}

// ---- main fused kernel ----
// Wave-exclusive rows: each wave owns 16 rows x 256 cols. No LDS, no barriers.
// A-strip (16 rows) loaded once fp32->bf16 into 8 afrag regs; B (WB, 128 KB,
// L2-resident) streamed per wave; epilogue reduction is fully wave-local.
__global__ __launch_bounds__(256, 3)
void hyp_main(const float* __restrict__ x, const short* __restrict__ WB,
              const float* __restrict__ s_buf, float* __restrict__ out){
  const int tid = threadIdx.x;
  const int wave = tid >> 6, lane = tid & 63;
  const int quad = lane >> 4, l15 = lane & 15;
  const int row0 = blockIdx.x * 64 + wave * 16;   // wave's rows: row0 .. row0+15

  // ---- A prologue: lane loads row (row0+l15), k = quad*8 + ks*32 .. +8 ----
  const float* xb = x + (size_t)(row0 + l15) * 256 + quad * 8;
  bf16x8 afrag[8];
  float pn = 0.f;
  #pragma unroll
  for (int ks = 0; ks < 8; ks++){
    const float4* p = (const float4*)(xb + ks * 32);
    float4 v0 = p[0];
    float4 v1 = p[1];
    bf16x8 a;
    a[0] = f2bf(v0.x); a[1] = f2bf(v0.y); a[2] = f2bf(v0.z); a[3] = f2bf(v0.w);
    a[4] = f2bf(v1.x); a[5] = f2bf(v1.y); a[6] = f2bf(v1.z); a[7] = f2bf(v1.w);
    afrag[ks] = a;
    pn += v0.x*v0.x + v0.y*v0.y + v0.z*v0.z + v0.w*v0.w
        + v1.x*v1.x + v1.y*v1.y + v1.z*v1.z + v1.w*v1.w;
  }
  // full fp32 norm of row (row0+l15): reduce over the quad bits
  pn += __shfl_xor(pn, 16, 64);
  pn += __shfl_xor(pn, 32, 64);

  // ---- MFMA: 16 col-tiles x 8 k-slices, B streamed from L2 ----
  f32x4 acc[16];
  #pragma unroll
  for (int tn = 0; tn < 16; tn++) acc[tn] = (f32x4){0.f, 0.f, 0.f, 0.f};

  const bf16x8* WBv = (const bf16x8*)WB;
  #pragma unroll
  for (int tn = 0; tn < 16; tn++){
    bf16x8 bf[8];
    #pragma unroll
    for (int ks = 0; ks < 8; ks++) bf[ks] = WBv[(tn * 8 + ks) * 64 + lane];
    #pragma unroll
    for (int ks = 0; ks < 8; ks++)
      acc[tn] = __builtin_amdgcn_mfma_f32_16x16x32_bf16(afrag[ks], bf[ks], acc[tn], 0, 0, 0);
  }

  // ---- epilogue: per-row sum(mx^2), sum(mx*s) — wave-local ----
  float sv[16];
  #pragma unroll
  for (int tn = 0; tn < 16; tn++) sv[tn] = s_buf[tn * 16 + l15];

  float msq[4] = {0.f,0.f,0.f,0.f}, mds[4] = {0.f,0.f,0.f,0.f};
  #pragma unroll
  for (int tn = 0; tn < 16; tn++)
    #pragma unroll
    for (int r = 0; r < 4; r++){
      float c = acc[tn][r];
      msq[r] += c * c;
      mds[r] += c * sv[tn];
    }
  #pragma unroll
  for (int m = 1; m < 16; m <<= 1)
    #pragma unroll
    for (int r = 0; r < 4; r++){
      msq[r] += __shfl_xor(msq[r], m, 64);
      mds[r] += __shfl_xor(mds[r], m, 64);
    }

  // ---- per-row scalars: one row per lane (row = quad*4 + (l15&3)), then broadcast ----
  int rr = l15 & 3;
  float ms = rr == 0 ? msq[0] : (rr == 1 ? msq[1] : (rr == 2 ? msq[2] : msq[3]));
  float md = rr == 0 ? mds[0] : (rr == 1 ? mds[1] : (rr == 2 ? mds[2] : mds[3]));
  float xn2 = __shfl(pn, (quad << 2) + rr, 64);   // norm of row quad*4+rr (held at lane l15=quad*4+rr)
  float s2 = s_buf[256];

  float xn = fmaxf(sqrtf(xn2), EPS);
  float xc = fminf(xn, 1.0f - 1e-7f);
  float art = 0.5f * (log1pf(xc) - log1pf(-xc));
  float mxn = fmaxf(sqrtf(ms), EPS);
  float tt = tanhf(mxn / xn * art);
  float te = fminf(tt, MAX_NORM);      // proj(res): ||res|| = te
  float sr = te / mxn;                 // res = sr * mx
  float r2 = te * te;
  float xy = sr * md;                  // <res, s>
  float aa = 1.0f + 2.0f * xy + s2;
  float bc = 1.0f - r2;
  float den = fmaxf(1.0f + 2.0f * xy + r2 * s2, EPS);
  float Pv = aa * sr / den, Qv = bc / den;
  float num2 = aa * aa * r2 + 2.0f * aa * bc * xy + bc * bc * s2;
  float on = fmaxf(sqrtf(num2) / den, EPS);
  if (on > MAX_NORM){ float fsc = MAX_NORM / on; Pv *= fsc; Qv *= fsc; }

  float P[4], Q[4];
  #pragma unroll
  for (int r = 0; r < 4; r++){
    P[r] = __shfl(Pv, (lane & 48) + r, 64);   // from lane (quad*16 + r), which owns row quad*4+r
    Q[r] = __shfl(Qv, (lane & 48) + r, 64);
  }

  // ---- store: out = P*mx + Q*s ----
  float* orow = out + (size_t)row0 * 256;
  #pragma unroll
  for (int tn = 0; tn < 16; tn++)
    #pragma unroll
    for (int r = 0; r < 4; r++)
      orow[(size_t)((quad * 4 + r) * 256 + tn * 16 + l15)] = P[r] * acc[tn][r] + Q[r] * sv[tn];
}

extern "C" void kernel_launch(void* const* d_in, const int* in_sizes, int n_in,
                              void* d_out, int out_size, void* d_ws, size_t ws_size,
                              hipStream_t stream){
  const float* x = (const float*)d_in[0];
  const float* W = (const float*)d_in[1];
  const float* b = (const float*)d_in[2];
  float* out = (float*)d_out;

  short* WB    = (short*)d_ws;                          // 256*256 bf16 = 128 KB
  float* s_buf = (float*)((char*)d_ws + 256 * 256 * 2); // 257 floats

  int N = in_sizes[0] / 256;

  setup_s_kernel<<<1, 256, 0, stream>>>(b, s_buf);
  conv_w_kernel<<<256, 256, 0, stream>>>(W, WB);
  hyp_main<<<N / 64, 256, 0, stream>>>(x, WB, s_buf, out);
}

// Round 4
// 464.797 us; speedup vs baseline: 2.8758x; 1.0874x over previous
//
#include <hip/hip_runtime.h>

#define EPS 1e-7f
#define MAX_NORM (1.0f - 1e-5f)

typedef __attribute__((ext_vector_type(8))) short bf16x8;
typedef __attribute__((ext_vector_type(4))) float f32x4;

__device__ __forceinline__ short f2bf(float f){
  unsigned u = __builtin_bit_cast(unsigned, f);
  u = (u + 0x7fffu + ((u >> 16) & 1u)) >> 16;
  return (short)u;
}

// ---- setup: s = tanh(||b||) * b / ||b||, s_buf[256] = s, s_buf[256] (extra) = ||s||^2 ----
__global__ void setup_s_kernel(const float* __restrict__ b, float* __restrict__ s_buf){
  __shared__ float redv[256];
  int t = threadIdx.x;
  float v = b[t];
  redv[t] = v * v;
  __syncthreads();
  for (int off = 128; off > 0; off >>= 1){
    if (t < off) redv[t] += redv[t + off];
    __syncthreads();
  }
  float bn = sqrtf(redv[0]);
  float th = tanhf(bn);
  s_buf[t] = th * v / fmaxf(bn, EPS);
  if (t == 0) s_buf[256] = th * th;
}

// ---- setup: W fp32 [256][256] -> bf16 in B-fragment-native layout ----
// flat = (((n>>4)*8 + ks)*4 + q)*16 + (n&15))*8 + j  with k = ks*32 + q*8 + j
__global__ void conv_w_kernel(const float* __restrict__ W, short* __restrict__ WB){
  int idx = blockIdx.x * 256 + threadIdx.x;
  int n = idx >> 8, k = idx & 255;
  int ks = k >> 5, q = (k >> 3) & 3, j = k & 7;
  int dst = ((((n >> 4) * 8 + ks) * 4 + q) * 16 + (n & 15)) * 8 + j;
  WB[dst] = f2bf(W[idx]);
}

// ---- main fused kernel: 32 rows x 256 cols per workgroup, 8 WGs/CU ----
// A-tile shared via LDS (18 KB -> 8 blocks/CU); each wave owns 64 cols.
// Row norms computed in fp32 during staging (8-lane shfl reduce).
__global__ __launch_bounds__(256, 4)
void hyp_main(const float* __restrict__ x, const short* __restrict__ WB,
              const float* __restrict__ s_buf, float* __restrict__ out){
  __shared__ __align__(16) short A_lds[32 * 264];   // 32 rows x 256 k bf16, stride 264
  __shared__ float redp[4][32][2];
  __shared__ float pq[32][2];
  __shared__ float xn2s[32];

  const int tid = threadIdx.x;
  const int wave = tid >> 6, lane = tid & 63;
  const int quad = lane >> 4, l15 = lane & 15;
  const int m0 = blockIdx.x * 32;

  // ---- stage A: thread t loads row t>>3, floats [seg*32, seg*32+32) ----
  {
    const int row = tid >> 3, seg = tid & 7;
    const float4* xr = (const float4*)(x + (size_t)(m0 + row) * 256 + seg * 32);
    float pn = 0.f;
    #pragma unroll
    for (int i = 0; i < 4; i++){
      float4 v0 = xr[2 * i];
      float4 v1 = xr[2 * i + 1];
      bf16x8 a;
      a[0] = f2bf(v0.x); a[1] = f2bf(v0.y); a[2] = f2bf(v0.z); a[3] = f2bf(v0.w);
      a[4] = f2bf(v1.x); a[5] = f2bf(v1.y); a[6] = f2bf(v1.z); a[7] = f2bf(v1.w);
      *(bf16x8*)&A_lds[row * 264 + seg * 32 + i * 8] = a;
      pn += v0.x*v0.x + v0.y*v0.y + v0.z*v0.z + v0.w*v0.w
          + v1.x*v1.x + v1.y*v1.y + v1.z*v1.z + v1.w*v1.w;
    }
    // reduce over the 8 threads (consecutive lanes) sharing this row
    pn += __shfl_xor(pn, 1, 64);
    pn += __shfl_xor(pn, 2, 64);
    pn += __shfl_xor(pn, 4, 64);
    if (seg == 0) xn2s[row] = pn;
  }
  __syncthreads();

  // ---- MFMA: wave owns cols wave*64..+63 (4 tn), rows 0..31 (2 mt) ----
  f32x4 acc[2][4];
  #pragma unroll
  for (int mt = 0; mt < 2; mt++)
    #pragma unroll
    for (int tn = 0; tn < 4; tn++) acc[mt][tn] = (f32x4){0.f, 0.f, 0.f, 0.f};

  const bf16x8* WBv = (const bf16x8*)WB;
  #pragma unroll
  for (int ks = 0; ks < 8; ks++){
    bf16x8 bfrag[4], afrag[2];
    #pragma unroll
    for (int tn = 0; tn < 4; tn++)
      bfrag[tn] = WBv[((wave * 4 + tn) * 8 + ks) * 64 + lane];
    #pragma unroll
    for (int mt = 0; mt < 2; mt++)
      afrag[mt] = *(const bf16x8*)&A_lds[(mt * 16 + l15) * 264 + ks * 32 + quad * 8];
    #pragma unroll
    for (int mt = 0; mt < 2; mt++)
      #pragma unroll
      for (int tn = 0; tn < 4; tn++)
        acc[mt][tn] = __builtin_amdgcn_mfma_f32_16x16x32_bf16(afrag[mt], bfrag[tn], acc[mt][tn], 0, 0, 0);
  }

  // ---- epilogue: per-row sum(mx^2), sum(mx*s) ----
  float sv[4];
  #pragma unroll
  for (int tn = 0; tn < 4; tn++) sv[tn] = s_buf[wave * 64 + tn * 16 + l15];

  float msq[2][4], mds[2][4];
  #pragma unroll
  for (int mt = 0; mt < 2; mt++)
    #pragma unroll
    for (int r = 0; r < 4; r++){
      float a = 0.f, d = 0.f;
      #pragma unroll
      for (int tn = 0; tn < 4; tn++){ float c = acc[mt][tn][r]; a += c * c; d += c * sv[tn]; }
      msq[mt][r] = a; mds[mt][r] = d;
    }
  #pragma unroll
  for (int m = 1; m < 16; m <<= 1){
    #pragma unroll
    for (int mt = 0; mt < 2; mt++)
      #pragma unroll
      for (int r = 0; r < 4; r++){
        msq[mt][r] += __shfl_xor(msq[mt][r], m, 64);
        mds[mt][r] += __shfl_xor(mds[mt][r], m, 64);
      }
  }
  if (l15 == 0){
    #pragma unroll
    for (int mt = 0; mt < 2; mt++)
      #pragma unroll
      for (int r = 0; r < 4; r++){
        int row = mt * 16 + quad * 4 + r;
        redp[wave][row][0] = msq[mt][r];
        redp[wave][row][1] = mds[mt][r];
      }
  }
  __syncthreads();

  // per-row scalars P, Q (threads 0..31)
  if (tid < 32){
    int row = tid;
    float ms  = redp[0][row][0] + redp[1][row][0] + redp[2][row][0] + redp[3][row][0];
    float md  = redp[0][row][1] + redp[1][row][1] + redp[2][row][1] + redp[3][row][1];
    float xn2 = xn2s[row];
    float s2 = s_buf[256];
    float xn = fmaxf(sqrtf(xn2), EPS);
    float xc = fminf(xn, 1.0f - 1e-7f);
    float art = 0.5f * (log1pf(xc) - log1pf(-xc));
    float mxn = fmaxf(sqrtf(ms), EPS);
    float tt = tanhf(mxn / xn * art);
    float te = fminf(tt, MAX_NORM);      // proj(res): ||res|| = te
    float sr = te / mxn;                 // res = sr * mx
    float r2 = te * te;
    float xy = sr * md;                  // <res, s>
    float aa = 1.0f + 2.0f * xy + s2;
    float bc = 1.0f - r2;
    float den = fmaxf(1.0f + 2.0f * xy + r2 * s2, EPS);
    float P = aa * sr / den, Q = bc / den;
    float num2 = aa * aa * r2 + 2.0f * aa * bc * xy + bc * bc * s2;
    float on = fmaxf(sqrtf(num2) / den, EPS);
    if (on > MAX_NORM){ float fsc = MAX_NORM / on; P *= fsc; Q *= fsc; }
    pq[row][0] = P; pq[row][1] = Q;
  }
  __syncthreads();

  // ---- store: out = P*mx + Q*s ----
  float* orow = out + (size_t)m0 * 256;
  #pragma unroll
  for (int mt = 0; mt < 2; mt++)
    #pragma unroll
    for (int r = 0; r < 4; r++){
      int row = mt * 16 + quad * 4 + r;
      float P = pq[row][0], Q = pq[row][1];
      #pragma unroll
      for (int tn = 0; tn < 4; tn++)
        orow[(size_t)row * 256 + wave * 64 + tn * 16 + l15] = P * acc[mt][tn][r] + Q * sv[tn];
    }
}

extern "C" void kernel_launch(void* const* d_in, const int* in_sizes, int n_in,
                              void* d_out, int out_size, void* d_ws, size_t ws_size,
                              hipStream_t stream){
  const float* x = (const float*)d_in[0];
  const float* W = (const float*)d_in[1];
  const float* b = (const float*)d_in[2];
  float* out = (float*)d_out;

  short* WB    = (short*)d_ws;                          // 256*256 bf16 = 128 KB
  float* s_buf = (float*)((char*)d_ws + 256 * 256 * 2); // 257 floats

  int N = in_sizes[0] / 256;

  setup_s_kernel<<<1, 256, 0, stream>>>(b, s_buf);
  conv_w_kernel<<<256, 256, 0, stream>>>(W, WB);
  hyp_main<<<N / 32, 256, 0, stream>>>(x, WB, s_buf, out);
}